// Round 1
// 247.012 us; speedup vs baseline: 1.1518x; 1.1518x over previous
//
#include <hip/hip_runtime.h>
#include <hip/hip_bf16.h>

// ---- problem constants (fixed by setup_inputs) ----
#define NB 2
#define LQ 19947
#define LV 19947
#define DM 256
#define NH 8
#define NL 4
#define NP 4
#define MROWS (NB*LQ)      // 39894 (even -> QPB=2 divides exactly)
#define MPAD  39936        // 312*128
#define QPB 2              // queries per block (1 wave per query, 128-thr blocks)

__device__ __constant__ int c_lvlH[4] = {100, 50, 25, 13};
__device__ __constant__ int c_lvlW[4] = {150, 75, 38, 19};
__device__ __constant__ int c_lvlS[4] = {0, 15000, 18750, 19700};

typedef __attribute__((ext_vector_type(8))) short short8;   // 8 bf16 (4 VGPRs)
typedef __attribute__((ext_vector_type(4))) float f32x4;
typedef __attribute__((ext_vector_type(2))) float f32x2;

__device__ __forceinline__ unsigned short f2bf(float f) {   // RTNE fp32->bf16
  unsigned u = __float_as_uint(f);
  u += 0x7FFFu + ((u >> 16) & 1u);
  return (unsigned short)(u >> 16);
}
__device__ __forceinline__ float bfl(unsigned u) { return __uint_as_float(u << 16); }
__device__ __forceinline__ float bfh(unsigned u) { return __uint_as_float(u & 0xFFFF0000u); }
// unpack dword holding 2 bf16 -> float2 (2 VALU: v_lshlrev + v_and)
__device__ __forceinline__ f32x2 up2(unsigned u) {
  f32x2 r; r.x = __uint_as_float(u << 16); r.y = __uint_as_float(u & 0xFFFF0000u); return r;
}

// ---------------------------------------------------------------------------
// ALL conversions in one kernel: xin->xb, query->qb (zero-padded to MPAD),
// W_val/W_samp/W_attn/W_out -> bf16, bsa = concat(b_samp, b_attn) fp32.
// ---------------------------------------------------------------------------
#define CB_X 9984           // MPAD*256/1024
__global__ __launch_bounds__(256) void conv_all(
    const float* __restrict__ xin, const float* __restrict__ query,
    const float* __restrict__ Wv, const float* __restrict__ Wsamp,
    const float* __restrict__ Wattn, const float* __restrict__ Wout,
    const float* __restrict__ bsamp, const float* __restrict__ battn,
    unsigned short* __restrict__ xb, unsigned short* __restrict__ qb,
    unsigned short* __restrict__ wvb, unsigned short* __restrict__ wqb,
    unsigned short* __restrict__ wob, float* __restrict__ bsa)
{
  const int b = blockIdx.x, t = threadIdx.x;
  if (b == 2 * CB_X + 224) {                 // biases
    bsa[t] = bsamp[t];
    if (t < 128) bsa[256 + t] = battn[t];
    return;
  }
  const float* src; unsigned short* dst; int base, ns;
  if (b < CB_X)            { src = xin;   dst = xb;          base = b * 1024;                ns = MROWS * 256; }
  else if (b < 2*CB_X)     { src = query; dst = qb;          base = (b - CB_X) * 1024;       ns = MROWS * 256; }
  else if (b < 2*CB_X+64)  { src = Wv;    dst = wvb;         base = (b - 2*CB_X) * 1024;     ns = 65536; }
  else if (b < 2*CB_X+128) { src = Wsamp; dst = wqb;         base = (b - 2*CB_X-64) * 1024;  ns = 65536; }
  else if (b < 2*CB_X+160) { src = Wattn; dst = wqb + 65536; base = (b - 2*CB_X-128) * 1024; ns = 32768; }
  else                     { src = Wout;  dst = wob;         base = (b - 2*CB_X-160) * 1024; ns = 65536; }
  const int i = base + t * 4;
  ushort4 o;
  if (i + 4 <= ns) {
    const float4 v = *(const float4*)(src + i);
    o.x = f2bf(v.x); o.y = f2bf(v.y); o.z = f2bf(v.z); o.w = f2bf(v.w);
  } else {
    float vs[4];
    #pragma unroll
    for (int j = 0; j < 4; ++j) vs[j] = (i + j < ns) ? src[i + j] : 0.f;
    o.x = f2bf(vs[0]); o.y = f2bf(vs[1]); o.z = f2bf(vs[2]); o.w = f2bf(vs[3]);
  }
  *(ushort4*)(dst + i) = o;
}

// ---------------------------------------------------------------------------
// Fused FRONT GEMM (value proj + offsets/logits proj in one launch).
// ---------------------------------------------------------------------------
__global__ __launch_bounds__(256) void gemm_front(
    const unsigned short* __restrict__ xb, const unsigned short* __restrict__ qb,
    const unsigned short* __restrict__ wvb, const unsigned short* __restrict__ wqb,
    const float* __restrict__ b_val, const float* __restrict__ bsa,
    unsigned short* __restrict__ value, unsigned short* __restrict__ oc)
{
  const unsigned short* Ab; const unsigned short* Wb; const float* bias;
  unsigned short* Cp; int Nn, cb;
  if (blockIdx.y < 2) { Ab = xb; Wb = wvb; bias = b_val; Cp = value; Nn = 256; cb = blockIdx.y; }
  else                { Ab = qb; Wb = wqb; bias = bsa;   Cp = oc;    Nn = 384; cb = blockIdx.y - 2; }

  __shared__ alignas(16) short As[128 * 32];
  __shared__ alignas(16) short Bs[128 * 32];

  const int t = threadIdx.x;
  const int w = t >> 6, l = t & 63;
  const int wr = w >> 1, wc = w & 1;
  const size_t rowBase = (size_t)blockIdx.x * 128;
  const int colBase = cb * 128;

  const f32x4 z = {0.f, 0.f, 0.f, 0.f};
  f32x4 acc[4][4];
  #pragma unroll
  for (int i = 0; i < 4; ++i)
    #pragma unroll
    for (int j = 0; j < 4; ++j) acc[i][j] = z;

  const int srow = l >> 2;
  const int scol = (l & 3) * 8;

  for (int ks = 0; ks < 8; ++ks) {
    const int k0 = ks * 32;
    #pragma unroll
    for (int i = 0; i < 2; ++i) {
      const int ii = w * 2 + i;
      const unsigned short* gA = Ab + (rowBase + ii * 16 + srow) * 256 + k0 + scol;
      __builtin_amdgcn_global_load_lds(
          (const __attribute__((address_space(1))) void*)gA,
          (__attribute__((address_space(3))) void*)&As[ii * 512], 16, 0, 0);
      const unsigned short* gB = Wb + ((size_t)(colBase + ii * 16 + srow)) * 256 + k0 + scol;
      __builtin_amdgcn_global_load_lds(
          (const __attribute__((address_space(1))) void*)gB,
          (__attribute__((address_space(3))) void*)&Bs[ii * 512], 16, 0, 0);
    }
    __syncthreads();
    short8 af[4], bf[4];
    #pragma unroll
    for (int i = 0; i < 4; ++i) {
      af[i] = *(const short8*)&As[(wr * 64 + i * 16 + (l & 15)) * 32 + (l >> 4) * 8];
      bf[i] = *(const short8*)&Bs[(wc * 64 + i * 16 + (l & 15)) * 32 + (l >> 4) * 8];
    }
    #pragma unroll
    for (int i = 0; i < 4; ++i)
      #pragma unroll
      for (int j = 0; j < 4; ++j)
        acc[i][j] = __builtin_amdgcn_mfma_f32_16x16x32_bf16(bf[j], af[i], acc[i][j], 0, 0, 0);
    __syncthreads();
  }

  const int row0 = (int)rowBase + wr * 64 + (l & 15);
  const int col0 = colBase + wc * 64 + (l >> 4) * 4;
  #pragma unroll
  for (int j = 0; j < 4; ++j) {
    const float4 bj = *(const float4*)(bias + col0 + j * 16);
    #pragma unroll
    for (int i = 0; i < 4; ++i) {
      const int row = row0 + i * 16;
      uint2 st;
      st.x = (unsigned)f2bf(acc[i][j][0] + bj.x) | ((unsigned)f2bf(acc[i][j][1] + bj.y) << 16);
      st.y = (unsigned)f2bf(acc[i][j][2] + bj.z) | ((unsigned)f2bf(acc[i][j][3] + bj.w) << 16);
      *(uint2*)(Cp + (size_t)row * Nn + col0 + j * 16) = st;
    }
  }
}

// ---------------------------------------------------------------------------
// Output GEMM: out = accb @ wob^T + b_out, fp32 out, row guard at MROWS.
// ---------------------------------------------------------------------------
__global__ __launch_bounds__(256) void gemm_out(
    const unsigned short* __restrict__ Ab, const unsigned short* __restrict__ Wb,
    const float* __restrict__ bias, float* __restrict__ Cp)
{
  __shared__ alignas(16) short As[128 * 32];
  __shared__ alignas(16) short Bs[128 * 32];

  const int t = threadIdx.x;
  const int w = t >> 6, l = t & 63;
  const int wr = w >> 1, wc = w & 1;
  const size_t rowBase = (size_t)blockIdx.x * 128;
  const int colBase = blockIdx.y * 128;

  const f32x4 z = {0.f, 0.f, 0.f, 0.f};
  f32x4 acc[4][4];
  #pragma unroll
  for (int i = 0; i < 4; ++i)
    #pragma unroll
    for (int j = 0; j < 4; ++j) acc[i][j] = z;

  const int srow = l >> 2;
  const int scol = (l & 3) * 8;

  for (int ks = 0; ks < 8; ++ks) {
    const int k0 = ks * 32;
    #pragma unroll
    for (int i = 0; i < 2; ++i) {
      const int ii = w * 2 + i;
      const unsigned short* gA = Ab + (rowBase + ii * 16 + srow) * 256 + k0 + scol;
      __builtin_amdgcn_global_load_lds(
          (const __attribute__((address_space(1))) void*)gA,
          (__attribute__((address_space(3))) void*)&As[ii * 512], 16, 0, 0);
      const unsigned short* gB = Wb + ((size_t)(colBase + ii * 16 + srow)) * 256 + k0 + scol;
      __builtin_amdgcn_global_load_lds(
          (const __attribute__((address_space(1))) void*)gB,
          (__attribute__((address_space(3))) void*)&Bs[ii * 512], 16, 0, 0);
    }
    __syncthreads();
    short8 af[4], bf[4];
    #pragma unroll
    for (int i = 0; i < 4; ++i) {
      af[i] = *(const short8*)&As[(wr * 64 + i * 16 + (l & 15)) * 32 + (l >> 4) * 8];
      bf[i] = *(const short8*)&Bs[(wc * 64 + i * 16 + (l & 15)) * 32 + (l >> 4) * 8];
    }
    #pragma unroll
    for (int i = 0; i < 4; ++i)
      #pragma unroll
      for (int j = 0; j < 4; ++j)
        acc[i][j] = __builtin_amdgcn_mfma_f32_16x16x32_bf16(bf[j], af[i], acc[i][j], 0, 0, 0);
    __syncthreads();
  }

  const int row0 = (int)rowBase + wr * 64 + (l & 15);
  const int col0 = colBase + wc * 64 + (l >> 4) * 4;
  #pragma unroll
  for (int j = 0; j < 4; ++j) {
    const float4 bj = *(const float4*)(bias + col0 + j * 16);
    #pragma unroll
    for (int i = 0; i < 4; ++i) {
      const int row = row0 + i * 16;
      if (row < MROWS) {
        *(float4*)(Cp + (size_t)row * 256 + col0 + j * 16) =
            make_float4(acc[i][j][0] + bj.x, acc[i][j][1] + bj.y,
                        acc[i][j][2] + bj.z, acc[i][j][3] + bj.w);
      }
    }
  }
}

// ---------------------------------------------------------------------------
// Fused softmax + sampling, phase-D redesigned (see theory):
//  lane = h*8 + c2*4 + s; uint4 gathers (2 loads/idx); merged off+weight LDS
//  (1 ds_read_b128/idx); depth-3 register-rotated prefetch (~6 loads in
//  flight); float2 packed accumulate; shfl_xor(4) corner-pair combine.
// ---------------------------------------------------------------------------
__global__ __launch_bounds__(128) void msda_sample(
    const unsigned short* __restrict__ value,   // (NB, LV, 256) bf16
    const float* __restrict__ refp,             // (NB, LQ, 4, 2) fp32
    const unsigned short* __restrict__ oc,      // (MPAD, 384) bf16: off(256)||logits(128)
    unsigned short* __restrict__ accb)          // (MPAD, 256) bf16 out
{
  __shared__ float s_aw[QPB][128];
  __shared__ float s_ref[QPB][8];
  // [q][h][idx][c2*4 + {offA, offB, bits(wA), bits(wB)}], idx-dim padded to 17
  __shared__ alignas(16) unsigned s_pk[QPB][NH][17][8];

  const int t = threadIdx.x;
  const int bq0 = blockIdx.x * QPB;            // MROWS even: no partial blocks

  // Phase A: logits -> LDS (upconvert), refs
  {
    const int q = t >> 6, i = t & 63;
    const int bq = bq0 + q;
    const unsigned pw = *(const unsigned*)(oc + (size_t)bq * 384 + 256 + i * 2);
    s_aw[q][i * 2 + 0] = bfl(pw);
    s_aw[q][i * 2 + 1] = bfh(pw);
    if (t < QPB * 8) {
      const int q2 = t >> 3, j = t & 7;
      s_ref[q2][j] = refp[(size_t)(bq0 + q2) * 8 + j];
    }
  }
  __syncthreads();

  // Phase B: per-(query,head) softmax over 16 logits
  if (t < QPB * NH) {
    const int q = t >> 3, h = t & 7;
    float* aw = &s_aw[q][h * 16];
    float m = aw[0];
    #pragma unroll
    for (int i = 1; i < 16; ++i) m = fmaxf(m, aw[i]);
    float e[16]; float s = 0.f;
    #pragma unroll
    for (int i = 0; i < 16; ++i) { e[i] = __expf(aw[i] - m); s += e[i]; }
    const float inv = 1.f / s;
    #pragma unroll
    for (int i = 0; i < 16; ++i) aw[i] = e[i] * inv;
  }
  __syncthreads();

  // Phase C: byte-offsets + folded weights packed per corner-pair
  #pragma unroll
  for (int it = t; it < QPB * 128; it += 128) {
    const int q = it >> 7, rem = it & 127;     // rem = h*16 + idx
    const int h = rem >> 4, idx = rem & 15;
    const int l = idx >> 2;
    const int bq = bq0 + q;
    const unsigned po = *(const unsigned*)(oc + (size_t)bq * 384 + rem * 2);
    const int Hl = c_lvlH[l], Wl = c_lvlW[l], st = c_lvlS[l];
    const float x = s_ref[q][l * 2 + 0] * (float)Wl - 0.5f + bfl(po);
    const float y = s_ref[q][l * 2 + 1] * (float)Hl - 0.5f + bfh(po);
    const float aw = s_aw[q][rem];
    const float x0f = floorf(x), y0f = floorf(y);
    const float lx = x - x0f, ly = y - y0f;
    const int x0 = (int)x0f, y0 = (int)y0f;
    const float vx0 = (x0 >= 0 && x0 < Wl) ? 1.f : 0.f;
    const float vx1 = (x0 >= -1 && x0 < Wl - 1) ? 1.f : 0.f;
    const float vy0 = (y0 >= 0 && y0 < Hl) ? 1.f : 0.f;
    const float vy1 = (y0 >= -1 && y0 < Hl - 1) ? 1.f : 0.f;
    const int xc0 = min(max(x0, 0), Wl - 1);
    const int xc1 = min(max(x0 + 1, 0), Wl - 1);
    const int yc0 = min(max(y0, 0), Hl - 1);
    const int yc1 = min(max(y0 + 1, 0), Hl - 1);
    const int r0 = st + yc0 * Wl, r1 = st + yc1 * Wl;
    uint4 g0, g1;
    g0.x = (unsigned)(r0 + xc0) * 512u;
    g0.y = (unsigned)(r0 + xc1) * 512u;
    g0.z = __float_as_uint((1.f - lx) * (1.f - ly) * aw * (vx0 * vy0));
    g0.w = __float_as_uint(lx * (1.f - ly) * aw * (vx1 * vy0));
    g1.x = (unsigned)(r1 + xc0) * 512u;
    g1.y = (unsigned)(r1 + xc1) * 512u;
    g1.z = __float_as_uint((1.f - lx) * ly * aw * (vx0 * vy1));
    g1.w = __float_as_uint(lx * ly * aw * (vx1 * vy1));
    *(uint4*)&s_pk[q][h][idx][0] = g0;
    *(uint4*)&s_pk[q][h][idx][4] = g1;
  }
  __syncthreads();

  // Phase D: pipelined gather + packed accumulate (1 wave per query)
  const int wv = t >> 6;
  const int lane = t & 63;
  const int bq = bq0 + wv;
  const int n = bq / LQ;                       // wave-uniform
  const char* vbase = (const char*)value + (size_t)n * LV * 512;
  const int h = lane >> 3;
  const int c2 = (lane >> 2) & 1;
  const unsigned laneoff = (unsigned)(h * 64 + (lane & 3) * 16);

  f32x2 acc0 = {0.f, 0.f}, acc1 = {0.f, 0.f}, acc2 = {0.f, 0.f}, acc3 = {0.f, 0.f};

#define PKRD(i) (*(const uint4*)&s_pk[wv][h][(i)][c2 * 4])
#define GLD(o)  (*(const uint4*)(vbase + (o) + laneoff))

  uint4 pk0 = PKRD(0), pk1 = PKRD(1), pk2 = PKRD(2), pk3 = PKRD(3);
  uint4 va0 = GLD(pk0.x), vb0 = GLD(pk0.y);
  uint4 va1 = GLD(pk1.x), vb1 = GLD(pk1.y);
  uint4 va2 = GLD(pk2.x), vb2 = GLD(pk2.y);

  #pragma unroll
  for (int idx = 0; idx < 16; ++idx) {
    uint4 va3, vb3, pk4;
    if (idx < 13) { va3 = GLD(pk3.x); vb3 = GLD(pk3.y); }
    if (idx < 12) { pk4 = PKRD(idx + 4); }
    const float was = __uint_as_float(pk0.z);
    const float wbs = __uint_as_float(pk0.w);
    f32x2 wa; wa.x = was; wa.y = was;
    f32x2 wb; wb.x = wbs; wb.y = wbs;
    acc0 = acc0 + wa * up2(va0.x);
    acc1 = acc1 + wa * up2(va0.y);
    acc2 = acc2 + wa * up2(va0.z);
    acc3 = acc3 + wa * up2(va0.w);
    acc0 = acc0 + wb * up2(vb0.x);
    acc1 = acc1 + wb * up2(vb0.y);
    acc2 = acc2 + wb * up2(vb0.z);
    acc3 = acc3 + wb * up2(vb0.w);
    pk0 = pk1; pk1 = pk2; pk2 = pk3; pk3 = pk4;
    va0 = va1; va1 = va2; va2 = va3;
    vb0 = vb1; vb1 = vb2; vb2 = vb3;
  }
#undef PKRD
#undef GLD

  // combine corner pairs (lane ^ 4 flips c2)
  acc0.x += __shfl_xor(acc0.x, 4); acc0.y += __shfl_xor(acc0.y, 4);
  acc1.x += __shfl_xor(acc1.x, 4); acc1.y += __shfl_xor(acc1.y, 4);
  acc2.x += __shfl_xor(acc2.x, 4); acc2.y += __shfl_xor(acc2.y, 4);
  acc3.x += __shfl_xor(acc3.x, 4); acc3.y += __shfl_xor(acc3.y, 4);

  if (c2 == 0) {
    uint4 st;
    st.x = (unsigned)f2bf(acc0.x) | ((unsigned)f2bf(acc0.y) << 16);
    st.y = (unsigned)f2bf(acc1.x) | ((unsigned)f2bf(acc1.y) << 16);
    st.z = (unsigned)f2bf(acc2.x) | ((unsigned)f2bf(acc2.y) << 16);
    st.w = (unsigned)f2bf(acc3.x) | ((unsigned)f2bf(acc3.y) << 16);
    *(uint4*)((char*)accb + (size_t)bq * 512 + laneoff) = st;
  }
}

// ---------------------------------------------------------------------------
extern "C" void kernel_launch(void* const* d_in, const int* in_sizes, int n_in,
                              void* d_out, int out_size, void* d_ws, size_t ws_size,
                              hipStream_t stream) {
  const float* query  = (const float*)d_in[0];
  const float* refp   = (const float*)d_in[1];
  const float* xin    = (const float*)d_in[2];
  const float* W_samp = (const float*)d_in[5];
  const float* b_samp = (const float*)d_in[6];
  const float* W_attn = (const float*)d_in[7];
  const float* b_attn = (const float*)d_in[8];
  const float* W_val  = (const float*)d_in[9];
  const float* b_val  = (const float*)d_in[10];
  const float* W_out  = (const float*)d_in[11];
  const float* b_out  = (const float*)d_in[12];
  float* out = (float*)d_out;
  (void)in_sizes; (void)n_in; (void)out_size; (void)ws_size;

  char* ws = (char*)d_ws;
  unsigned short* value = (unsigned short*)(ws);                 // MPAD*256 bf16
  unsigned short* qb    = (unsigned short*)(ws + 20447232);      // MPAD*256 bf16
  unsigned short* xb    = (unsigned short*)(ws + 40894464);      // MPAD*256 bf16
  unsigned short* accb  = xb;                                    // xb dead after gemm_front
  unsigned short* oc    = (unsigned short*)(ws + 61341696);      // MPAD*384 bf16
  unsigned short* wvb   = (unsigned short*)(ws + 92012544);      // 256x256
  unsigned short* wqb   = (unsigned short*)(ws + 92143616);      // 384x256 (samp||attn)
  unsigned short* wob   = (unsigned short*)(ws + 92340224);      // 256x256
  float*          bsa   = (float*)(ws + 92471296);               // 384 fp32

  hipLaunchKernelGGL(conv_all, dim3(2 * CB_X + 225), dim3(256), 0, stream,
                     xin, query, W_val, W_samp, W_attn, W_out, b_samp, b_attn,
                     xb, qb, wvb, wqb, wob, bsa);
  hipLaunchKernelGGL(gemm_front, dim3(312, 5), dim3(256), 0, stream,
                     xb, qb, wvb, wqb, b_val, bsa, value, oc);
  hipLaunchKernelGGL(msda_sample, dim3(MROWS / QPB), dim3(128), 0, stream,
                     value, refp, oc, accb);
  hipLaunchKernelGGL(gemm_out, dim3(312, 2), dim3(256), 0, stream,
                     accb, wob, b_out, out);
}